// Round 1
// baseline (10976.145 us; speedup 1.0000x reference)
//
#include <hip/hip_runtime.h>
#include <hip/hip_bf16.h>
#include <math.h>

// SportsGNN: ftMLP -> GATv2 x2 -> sumpool -> MLP -> softmax
// N=250000, E=5000000, H=2, O=8 (HO=16)

#define HO 16

__device__ __forceinline__ float lrelu(float x, float s) { return x > 0.f ? x : s * x; }

// monotone float <-> uint key for atomicMax on floats
__device__ __forceinline__ unsigned int fkey(float f) {
    unsigned int u = __float_as_uint(f);
    return (u & 0x80000000u) ? ~u : (u | 0x80000000u);
}
__device__ __forceinline__ float funkey(unsigned int u) {
    return (u & 0x80000000u) ? __uint_as_float(u & 0x7fffffffu) : __uint_as_float(~u);
}

// ---------------- node kernel, layer 1: x[N,3] -> ftMLP -> xl1,xr1 [N,16] ----------------
__global__ void __launch_bounds__(256) node_l1(
    const float* __restrict__ x,
    const float* __restrict__ ft1_w, const float* __restrict__ ft1_b,
    const float* __restrict__ ft2_w, const float* __restrict__ ft2_b,
    const float* __restrict__ wl, const float* __restrict__ bl,
    const float* __restrict__ wr, const float* __restrict__ br,
    float* __restrict__ xl, float* __restrict__ xr, int N)
{
    int n = blockIdx.x * 256 + threadIdx.x;
    if (n >= N) return;
    float x0 = x[3*n], x1 = x[3*n+1], x2 = x[3*n+2];
    float h1[8];
#pragma unroll
    for (int j = 0; j < 8; j++) {
        float a = ft1_w[3*j]*x0 + ft1_w[3*j+1]*x1 + ft1_w[3*j+2]*x2 + ft1_b[j];
        h1[j] = lrelu(a, 0.1f);
    }
    float h2[8];
#pragma unroll
    for (int j = 0; j < 8; j++) {
        float a = ft2_b[j];
#pragma unroll
        for (int k = 0; k < 8; k++) a += ft2_w[8*j+k]*h1[k];
        h2[j] = lrelu(a, 0.1f);
    }
    float ol[HO], orr[HO];
#pragma unroll
    for (int j = 0; j < HO; j++) {
        float a = bl[j], b = br[j];
#pragma unroll
        for (int k = 0; k < 8; k++) { a += wl[8*j+k]*h2[k]; b += wr[8*j+k]*h2[k]; }
        ol[j] = a; orr[j] = b;
    }
    float4* xl4 = (float4*)(xl + (size_t)n*HO);
    float4* xr4 = (float4*)(xr + (size_t)n*HO);
#pragma unroll
    for (int q = 0; q < 4; q++) {
        xl4[q] = make_float4(ol[4*q], ol[4*q+1], ol[4*q+2], ol[4*q+3]);
        xr4[q] = make_float4(orr[4*q], orr[4*q+1], orr[4*q+2], orr[4*q+3]);
    }
}

// ---------------- edge pass 1: logits + segment max ----------------
__global__ void __launch_bounds__(256) edge_pass1(
    const int* __restrict__ src, const int* __restrict__ dst,
    const float* __restrict__ eattr,
    const float* __restrict__ xl, const float* __restrict__ xr,
    const float* __restrict__ we, const float* __restrict__ att,
    float2* __restrict__ logits, unsigned int* __restrict__ mx, int E)
{
    int e = blockIdx.x * 256 + threadIdx.x;
    if (e >= E) return;
    int s = src[e], d = dst[e];
    float ea0 = eattr[2*e], ea1 = eattr[2*e+1];
    const float4* xls4 = (const float4*)(xl + (size_t)s*HO);
    const float4* xrd4 = (const float4*)(xr + (size_t)d*HO);
    float xs[HO], xd[HO];
#pragma unroll
    for (int q = 0; q < 4; q++) {
        float4 a = xls4[q]; xs[4*q]=a.x; xs[4*q+1]=a.y; xs[4*q+2]=a.z; xs[4*q+3]=a.w;
        float4 b = xrd4[q]; xd[4*q]=b.x; xd[4*q+1]=b.y; xd[4*q+2]=b.z; xd[4*q+3]=b.w;
    }
    float lg[2];
#pragma unroll
    for (int h = 0; h < 2; h++) {
        float acc = 0.f;
#pragma unroll
        for (int o = 0; o < 8; o++) {
            int k = h*8 + o;
            float ev = we[2*k]*ea0 + we[2*k+1]*ea1;
            float mv = xs[k] + xd[k] + ev;
            mv = mv > 0.f ? mv : 0.2f*mv;      // leaky_relu 0.2
            acc += mv * att[k];
        }
        lg[h] = acc;
    }
    logits[e] = make_float2(lg[0], lg[1]);
    atomicMax(&mx[2*(size_t)d],   fkey(lg[0]));
    atomicMax(&mx[2*(size_t)d+1], fkey(lg[1]));
}

// ---------------- edge pass 2: exp + denom + weighted numerator scatter ----------------
__global__ void __launch_bounds__(256) edge_pass2(
    const int* __restrict__ src, const int* __restrict__ dst,
    const float2* __restrict__ logits, const unsigned int* __restrict__ mx,
    const float* __restrict__ xl,
    float* __restrict__ denom, float* __restrict__ num, int E)
{
    int e = blockIdx.x * 256 + threadIdx.x;
    if (e >= E) return;
    int s = src[e], d = dst[e];
    float2 lg = logits[e];
    float a0 = __expf(lg.x - funkey(mx[2*(size_t)d]));
    float a1 = __expf(lg.y - funkey(mx[2*(size_t)d+1]));
    atomicAdd(&denom[2*(size_t)d],   a0);
    atomicAdd(&denom[2*(size_t)d+1], a1);
    const float4* xls4 = (const float4*)(xl + (size_t)s*HO);
    float* nd = num + (size_t)d*HO;
#pragma unroll
    for (int q = 0; q < 4; q++) {
        float4 a = xls4[q];
        float w = (q < 2) ? a0 : a1;   // head 0 = elems 0..7, head 1 = 8..15
        atomicAdd(nd + 4*q + 0, w*a.x);
        atomicAdd(nd + 4*q + 1, w*a.y);
        atomicAdd(nd + 4*q + 2, w*a.z);
        atomicAdd(nd + 4*q + 3, w*a.w);
    }
}

// ---------------- node pass 3 (after layer 1): finish + lrelu + layer-2 transforms ----------------
__global__ void __launch_bounds__(256) node_p3_l1(
    const float* __restrict__ num, const float* __restrict__ denom,
    const float* __restrict__ bias,
    const float* __restrict__ wl2, const float* __restrict__ bl2,
    const float* __restrict__ wr2, const float* __restrict__ br2,
    float* __restrict__ xl2, float* __restrict__ xr2, int N)
{
    int n = blockIdx.x * 256 + threadIdx.x;
    if (n >= N) return;
    float dn0 = denom[2*(size_t)n] + 1e-16f, dn1 = denom[2*(size_t)n+1] + 1e-16f;
    float h[HO];
#pragma unroll
    for (int k = 0; k < HO; k++) {
        float v = num[(size_t)n*HO + k] / (k < 8 ? dn0 : dn1) + bias[k];
        h[k] = lrelu(v, 0.1f);
    }
    float ol[HO], orr[HO];
#pragma unroll
    for (int j = 0; j < HO; j++) {
        float a = bl2[j], b = br2[j];
#pragma unroll
        for (int k = 0; k < HO; k++) { a += wl2[HO*j+k]*h[k]; b += wr2[HO*j+k]*h[k]; }
        ol[j] = a; orr[j] = b;
    }
    float4* xl4 = (float4*)(xl2 + (size_t)n*HO);
    float4* xr4 = (float4*)(xr2 + (size_t)n*HO);
#pragma unroll
    for (int q = 0; q < 4; q++) {
        xl4[q] = make_float4(ol[4*q], ol[4*q+1], ol[4*q+2], ol[4*q+3]);
        xr4[q] = make_float4(orr[4*q], orr[4*q+1], orr[4*q+2], orr[4*q+3]);
    }
}

// ---------------- node pass 3 (after layer 2): finish + sum-pool into pool[16] ----------------
__global__ void __launch_bounds__(256) node_p3_l2(
    const float* __restrict__ num, const float* __restrict__ denom,
    const float* __restrict__ bias, float* __restrict__ pool, int N)
{
    int n = blockIdx.x * 256 + threadIdx.x;
    bool valid = n < N;
    float v[HO];
    if (valid) {
        float dn0 = denom[2*(size_t)n] + 1e-16f, dn1 = denom[2*(size_t)n+1] + 1e-16f;
#pragma unroll
        for (int k = 0; k < HO; k++)
            v[k] = num[(size_t)n*HO + k] / (k < 8 ? dn0 : dn1) + bias[k];
    } else {
#pragma unroll
        for (int k = 0; k < HO; k++) v[k] = 0.f;
    }
    // wave-level reduce (64 lanes)
#pragma unroll
    for (int off = 32; off > 0; off >>= 1) {
#pragma unroll
        for (int k = 0; k < HO; k++) v[k] += __shfl_down(v[k], off, 64);
    }
    if ((threadIdx.x & 63) == 0) {
#pragma unroll
        for (int k = 0; k < HO; k++) atomicAdd(&pool[k], v[k]);
    }
}

// ---------------- final tail: pool MLP + meta encoder + fc chain + softmax ----------------
__global__ void __launch_bounds__(64) final_mlp(
    const float* __restrict__ pool, const float* __restrict__ meta,
    const float* __restrict__ sp1_w, const float* __restrict__ sp1_b,
    const float* __restrict__ sp2_w, const float* __restrict__ sp2_b,
    const float* __restrict__ me_w, const float* __restrict__ me_b,
    const float* __restrict__ fc1_w, const float* __restrict__ fc1_b,
    const float* __restrict__ fc2_w, const float* __restrict__ fc2_b,
    const float* __restrict__ fc3_w, const float* __restrict__ fc3_b,
    float* __restrict__ out)
{
    __shared__ float s1[64], zb[24], z1[24], z2[8];
    int t = threadIdx.x;
    {   // sp1: 16 -> 64, lrelu
        float acc = sp1_b[t];
        for (int k = 0; k < 16; k++) acc += pool[k]*sp1_w[t*16+k];
        s1[t] = lrelu(acc, 0.1f);
    }
    __syncthreads();
    if (t < 16) {          // sp2: 64 -> 16 (no act)
        float acc = sp2_b[t];
        for (int k = 0; k < 64; k++) acc += s1[k]*sp2_w[t*64+k];
        zb[t] = acc;
    } else if (t < 24) {   // meta encoder: 6 -> 8, lrelu
        int j = t - 16;
        float acc = me_b[j];
        for (int k = 0; k < 6; k++) acc += meta[k]*me_w[j*6+k];
        zb[t] = lrelu(acc, 0.1f);
    }
    __syncthreads();
    if (t < 24) {          // fc1: 24 -> 24, lrelu
        float acc = fc1_b[t];
        for (int k = 0; k < 24; k++) acc += zb[k]*fc1_w[t*24+k];
        z1[t] = lrelu(acc, 0.1f);
    }
    __syncthreads();
    if (t < 8) {           // fc2: 24 -> 8, lrelu
        float acc = fc2_b[t];
        for (int k = 0; k < 24; k++) acc += z1[k]*fc2_w[t*24+k];
        z2[t] = lrelu(acc, 0.1f);
    }
    __syncthreads();
    if (t == 0) {          // fc3: 8 -> 3, softmax
        float z3[3]; float mxv = -1e30f;
        for (int j = 0; j < 3; j++) {
            float acc = fc3_b[j];
            for (int k = 0; k < 8; k++) acc += z2[k]*fc3_w[j*8+k];
            z3[j] = acc; mxv = fmaxf(mxv, acc);
        }
        float s = 0.f;
        for (int j = 0; j < 3; j++) { z3[j] = __expf(z3[j]-mxv); s += z3[j]; }
        for (int j = 0; j < 3; j++) out[j] = z3[j]/s;
    }
}

extern "C" void kernel_launch(void* const* d_in, const int* in_sizes, int n_in,
                              void* d_out, int out_size, void* d_ws, size_t ws_size,
                              hipStream_t stream)
{
    const float* x      = (const float*)d_in[0];
    const int*   eidx   = (const int*)  d_in[1];
    const float* eattr  = (const float*)d_in[2];
    const float* meta   = (const float*)d_in[3];
    const float* ft1_w  = (const float*)d_in[4];
    const float* ft1_b  = (const float*)d_in[5];
    const float* ft2_w  = (const float*)d_in[6];
    const float* ft2_b  = (const float*)d_in[7];
    const float* g1_wl  = (const float*)d_in[8];
    const float* g1_bl  = (const float*)d_in[9];
    const float* g1_wr  = (const float*)d_in[10];
    const float* g1_br  = (const float*)d_in[11];
    const float* g1_we  = (const float*)d_in[12];
    const float* g1_att = (const float*)d_in[13];
    const float* g1_bias= (const float*)d_in[14];
    const float* g2_wl  = (const float*)d_in[15];
    const float* g2_bl  = (const float*)d_in[16];
    const float* g2_wr  = (const float*)d_in[17];
    const float* g2_br  = (const float*)d_in[18];
    const float* g2_we  = (const float*)d_in[19];
    const float* g2_att = (const float*)d_in[20];
    const float* g2_bias= (const float*)d_in[21];
    const float* sp1_w  = (const float*)d_in[22];
    const float* sp1_b  = (const float*)d_in[23];
    const float* sp2_w  = (const float*)d_in[24];
    const float* sp2_b  = (const float*)d_in[25];
    const float* me_w   = (const float*)d_in[26];
    const float* me_b   = (const float*)d_in[27];
    const float* fc1_w  = (const float*)d_in[28];
    const float* fc1_b  = (const float*)d_in[29];
    const float* fc2_w  = (const float*)d_in[30];
    const float* fc2_b  = (const float*)d_in[31];
    const float* fc3_w  = (const float*)d_in[32];
    const float* fc3_b  = (const float*)d_in[33];
    float* out = (float*)d_out;

    const int N = in_sizes[0] / 3;
    const int E = in_sizes[2] / 2;
    const int* src = eidx;
    const int* dst = eidx + E;

    // workspace layout (bytes):
    //   [0, 8N)            mx      (2N u32)  -- zeroed
    //   [8N, 16N)          denom   (2N f32)  -- zeroed
    //   [16N, 80N)         num     (16N f32) -- zeroed
    //   [80N, 80N+64)      pool    (16 f32)  -- zeroed
    //   [80N+64, 144N+64)  xl      (16N f32)
    //   [144N+64, 208N+64) xr      (16N f32)
    //   [208N+64, +8E)     logits  (2E f32)
    char* w = (char*)d_ws;
    unsigned int* mx  = (unsigned int*)w;
    float* denom      = (float*)(w + (size_t)8*N);
    float* num        = (float*)(w + (size_t)16*N);
    float* pool       = (float*)(w + (size_t)80*N);
    float* xl         = (float*)(w + (size_t)80*N + 64);
    float* xr         = (float*)(w + (size_t)144*N + 64);
    float2* logits    = (float2*)(w + (size_t)208*N + 64);
    const size_t zeroBytes = (size_t)80*N + 64;

    const int BN = (N + 255) / 256;
    const int BE = (E + 255) / 256;

    // ---- layer 1 ----
    hipMemsetAsync(d_ws, 0, zeroBytes, stream);
    node_l1<<<BN, 256, 0, stream>>>(x, ft1_w, ft1_b, ft2_w, ft2_b,
                                    g1_wl, g1_bl, g1_wr, g1_br, xl, xr, N);
    edge_pass1<<<BE, 256, 0, stream>>>(src, dst, eattr, xl, xr, g1_we, g1_att, logits, mx, E);
    edge_pass2<<<BE, 256, 0, stream>>>(src, dst, logits, mx, xl, denom, num, E);
    node_p3_l1<<<BN, 256, 0, stream>>>(num, denom, g1_bias,
                                       g2_wl, g2_bl, g2_wr, g2_br, xl, xr, N);
    // ---- layer 2 ----
    hipMemsetAsync(d_ws, 0, zeroBytes, stream);
    edge_pass1<<<BE, 256, 0, stream>>>(src, dst, eattr, xl, xr, g2_we, g2_att, logits, mx, E);
    edge_pass2<<<BE, 256, 0, stream>>>(src, dst, logits, mx, xl, denom, num, E);
    node_p3_l2<<<BN, 256, 0, stream>>>(num, denom, g2_bias, pool, N);
    // ---- tail ----
    final_mlp<<<1, 64, 0, stream>>>(pool, meta, sp1_w, sp1_b, sp2_w, sp2_b,
                                    me_w, me_b, fc1_w, fc1_b, fc2_w, fc2_b,
                                    fc3_w, fc3_b, out);
}

// Round 2
// 2490.116 us; speedup vs baseline: 4.4079x; 4.4079x over previous
//
#include <hip/hip_runtime.h>
#include <hip/hip_bf16.h>
#include <math.h>

// SportsGNN: ftMLP -> GATv2 x2 -> sumpool -> MLP -> softmax
// N=250000, E=5000000, H=2, O=8 (HO=16)
// Strategy: CSR-by-dst built once per launch; per-node single-pass
// online-softmax aggregation (no float atomics at all).

#define HO 16

__device__ __forceinline__ float lrelu(float x, float s) { return x > 0.f ? x : s * x; }

// ---------------- node kernel, layer 1: x[N,3] -> ftMLP -> xl1,xr1 [N,16] ----------------
__global__ void __launch_bounds__(256) node_l1(
    const float* __restrict__ x,
    const float* __restrict__ ft1_w, const float* __restrict__ ft1_b,
    const float* __restrict__ ft2_w, const float* __restrict__ ft2_b,
    const float* __restrict__ wl, const float* __restrict__ bl,
    const float* __restrict__ wr, const float* __restrict__ br,
    float* __restrict__ xl, float* __restrict__ xr, int N)
{
    int n = blockIdx.x * 256 + threadIdx.x;
    if (n >= N) return;
    float x0 = x[3*n], x1 = x[3*n+1], x2 = x[3*n+2];
    float h1[8];
#pragma unroll
    for (int j = 0; j < 8; j++) {
        float a = ft1_w[3*j]*x0 + ft1_w[3*j+1]*x1 + ft1_w[3*j+2]*x2 + ft1_b[j];
        h1[j] = lrelu(a, 0.1f);
    }
    float h2[8];
#pragma unroll
    for (int j = 0; j < 8; j++) {
        float a = ft2_b[j];
#pragma unroll
        for (int k = 0; k < 8; k++) a += ft2_w[8*j+k]*h1[k];
        h2[j] = lrelu(a, 0.1f);
    }
    float ol[HO], orr[HO];
#pragma unroll
    for (int j = 0; j < HO; j++) {
        float a = bl[j], b = br[j];
#pragma unroll
        for (int k = 0; k < 8; k++) { a += wl[8*j+k]*h2[k]; b += wr[8*j+k]*h2[k]; }
        ol[j] = a; orr[j] = b;
    }
    float4* xl4 = (float4*)(xl + (size_t)n*HO);
    float4* xr4 = (float4*)(xr + (size_t)n*HO);
#pragma unroll
    for (int q = 0; q < 4; q++) {
        xl4[q] = make_float4(ol[4*q], ol[4*q+1], ol[4*q+2], ol[4*q+3]);
        xr4[q] = make_float4(orr[4*q], orr[4*q+1], orr[4*q+2], orr[4*q+3]);
    }
}

// ---------------- CSR build ----------------
__global__ void __launch_bounds__(256) k_hist(
    const int* __restrict__ dst, int* __restrict__ deg, int E)
{
    int e = blockIdx.x * 256 + threadIdx.x;
    if (e < E) atomicAdd(&deg[dst[e]], 1);
}

// block sums of deg (256 per block)
__global__ void __launch_bounds__(256) k_scanA(
    const int* __restrict__ deg, int* __restrict__ bsum, int N)
{
    __shared__ int r[256];
    int t = threadIdx.x;
    int n = blockIdx.x * 256 + t;
    r[t] = (n < N) ? deg[n] : 0;
    __syncthreads();
#pragma unroll
    for (int off = 128; off > 0; off >>= 1) {
        if (t < off) r[t] += r[t + off];
        __syncthreads();
    }
    if (t == 0) bsum[blockIdx.x] = r[0];
}

// exclusive scan of block sums (nb <= 1024), single block of 1024 threads
__global__ void __launch_bounds__(1024) k_scanB(int* __restrict__ bsum, int nb)
{
    __shared__ int s[1024];
    int t = threadIdx.x;
    int v = (t < nb) ? bsum[t] : 0;
    s[t] = v;
    __syncthreads();
    for (int off = 1; off < 1024; off <<= 1) {
        int add = (t >= off) ? s[t - off] : 0;
        __syncthreads();
        s[t] += add;
        __syncthreads();
    }
    if (t < nb) bsum[t] = s[t] - v;   // exclusive
}

// final: row[n] = exclusive prefix; cursor[n] = same (scatter cursors); row[N]=E
__global__ void __launch_bounds__(256) k_scanC(
    int* deg_cursor, const int* __restrict__ bsum,
    int* __restrict__ row, int N, int E)
{
    __shared__ int s[256];
    int t = threadIdx.x;
    int n = blockIdx.x * 256 + t;
    int d = (n < N) ? deg_cursor[n] : 0;
    s[t] = d;
    __syncthreads();
    for (int off = 1; off < 256; off <<= 1) {
        int add = (t >= off) ? s[t - off] : 0;
        __syncthreads();
        s[t] += add;
        __syncthreads();
    }
    int val = bsum[blockIdx.x] + s[t] - d;   // exclusive prefix
    if (n < N) { row[n] = val; deg_cursor[n] = val; }
    if (n == 0) row[N] = E;
}

__global__ void __launch_bounds__(256) k_scatter(
    const int* __restrict__ dst, int* __restrict__ cursor,
    int* __restrict__ eperm, int E)
{
    int e = blockIdx.x * 256 + threadIdx.x;
    if (e >= E) return;
    int pos = atomicAdd(&cursor[dst[e]], 1);
    eperm[pos] = e;
}

// ---------------- per-edge logits (streaming, coalesced write) ----------------
__global__ void __launch_bounds__(256) edge_logits(
    const int* __restrict__ src, const int* __restrict__ dst,
    const float* __restrict__ eattr,
    const float* __restrict__ xl, const float* __restrict__ xr,
    const float* __restrict__ we, const float* __restrict__ att,
    float2* __restrict__ logits, int E)
{
    int e = blockIdx.x * 256 + threadIdx.x;
    if (e >= E) return;
    int s = src[e], d = dst[e];
    float ea0 = eattr[2*e], ea1 = eattr[2*e+1];
    const float4* xls4 = (const float4*)(xl + (size_t)s*HO);
    const float4* xrd4 = (const float4*)(xr + (size_t)d*HO);
    float xs[HO], xd[HO];
#pragma unroll
    for (int q = 0; q < 4; q++) {
        float4 a = xls4[q]; xs[4*q]=a.x; xs[4*q+1]=a.y; xs[4*q+2]=a.z; xs[4*q+3]=a.w;
        float4 b = xrd4[q]; xd[4*q]=b.x; xd[4*q+1]=b.y; xd[4*q+2]=b.z; xd[4*q+3]=b.w;
    }
    float lg[2];
#pragma unroll
    for (int h = 0; h < 2; h++) {
        float acc = 0.f;
#pragma unroll
        for (int o = 0; o < 8; o++) {
            int k = h*8 + o;
            float ev = we[2*k]*ea0 + we[2*k+1]*ea1;
            float mv = xs[k] + xd[k] + ev;
            mv = mv > 0.f ? mv : 0.2f*mv;      // leaky_relu 0.2
            acc += mv * att[k];
        }
        lg[h] = acc;
    }
    logits[e] = make_float2(lg[0], lg[1]);
}

// ---------------- per-node online-softmax aggregation (no atomics) ----------------
// Computes h[n] = sum_e alpha_e * xl[src_e] / denom + bias, writes to hout.
// mode 0: lrelu(0.1) then store; mode 1: store raw (layer-2 path pools separately)
__device__ __forceinline__ void agg_node(
    int n, const int* __restrict__ row, const int* __restrict__ eperm,
    const float2* __restrict__ logits, const int* __restrict__ src,
    const float* __restrict__ xl, const float* __restrict__ bias,
    float* h)
{
    int beg = row[n], end = row[n+1];
    float m0 = -INFINITY, m1 = -INFINITY, s0 = 0.f, s1 = 0.f;
    float acc[HO];
#pragma unroll
    for (int k = 0; k < HO; k++) acc[k] = 0.f;
    for (int i = beg; i < end; i++) {
        int e = eperm[i];
        float2 lg = logits[e];
        int sidx = src[e];
        const float4* xp = (const float4*)(xl + (size_t)sidx*HO);
        float4 v0 = xp[0], v1 = xp[1], v2 = xp[2], v3 = xp[3];
        float nm0 = fmaxf(m0, lg.x), nm1 = fmaxf(m1, lg.y);
        float al = __expf(m0 - nm0), be = __expf(m1 - nm1);
        float a0 = __expf(lg.x - nm0), a1 = __expf(lg.y - nm1);
        s0 = s0*al + a0; s1 = s1*be + a1;
        m0 = nm0; m1 = nm1;
        acc[0]  = acc[0]*al + a0*v0.x;  acc[1]  = acc[1]*al + a0*v0.y;
        acc[2]  = acc[2]*al + a0*v0.z;  acc[3]  = acc[3]*al + a0*v0.w;
        acc[4]  = acc[4]*al + a0*v1.x;  acc[5]  = acc[5]*al + a0*v1.y;
        acc[6]  = acc[6]*al + a0*v1.z;  acc[7]  = acc[7]*al + a0*v1.w;
        acc[8]  = acc[8]*be + a1*v2.x;  acc[9]  = acc[9]*be + a1*v2.y;
        acc[10] = acc[10]*be + a1*v2.z; acc[11] = acc[11]*be + a1*v2.w;
        acc[12] = acc[12]*be + a1*v3.x; acc[13] = acc[13]*be + a1*v3.y;
        acc[14] = acc[14]*be + a1*v3.z; acc[15] = acc[15]*be + a1*v3.w;
    }
    float i0 = 1.f/(s0 + 1e-16f), i1 = 1.f/(s1 + 1e-16f);
#pragma unroll
    for (int k = 0; k < HO; k++) h[k] = acc[k]*(k < 8 ? i0 : i1) + bias[k];
}

// layer 1: aggregate + lrelu(0.1), write h -> hout (aliased into xr buffer)
__global__ void __launch_bounds__(256) node_agg_l1(
    const int* __restrict__ row, const int* __restrict__ eperm,
    const float2* __restrict__ logits, const int* __restrict__ src,
    const float* __restrict__ xl, const float* __restrict__ bias,
    float* __restrict__ hout, int N)
{
    int n = blockIdx.x * 256 + threadIdx.x;
    if (n >= N) return;
    float h[HO];
    agg_node(n, row, eperm, logits, src, xl, bias, h);
    float4* hp = (float4*)(hout + (size_t)n*HO);
#pragma unroll
    for (int q = 0; q < 4; q++)
        hp[q] = make_float4(lrelu(h[4*q],0.1f), lrelu(h[4*q+1],0.1f),
                            lrelu(h[4*q+2],0.1f), lrelu(h[4*q+3],0.1f));
}

// transform h (in xr buffer) by layer-2 weights -> xl2, xr2 (xr2 aliases h: no __restrict__)
__global__ void __launch_bounds__(256) node_transform(
    const float* hin,
    const float* __restrict__ wl2, const float* __restrict__ bl2,
    const float* __restrict__ wr2, const float* __restrict__ br2,
    float* __restrict__ xl2, float* xr2, int N)
{
    int n = blockIdx.x * 256 + threadIdx.x;
    if (n >= N) return;
    float h[HO];
    const float4* hp = (const float4*)(hin + (size_t)n*HO);
#pragma unroll
    for (int q = 0; q < 4; q++) {
        float4 v = hp[q];
        h[4*q]=v.x; h[4*q+1]=v.y; h[4*q+2]=v.z; h[4*q+3]=v.w;
    }
    float ol[HO], orr[HO];
#pragma unroll
    for (int j = 0; j < HO; j++) {
        float a = bl2[j], b = br2[j];
#pragma unroll
        for (int k = 0; k < HO; k++) { a += wl2[HO*j+k]*h[k]; b += wr2[HO*j+k]*h[k]; }
        ol[j] = a; orr[j] = b;
    }
    float4* xl4 = (float4*)(xl2 + (size_t)n*HO);
    float4* xr4 = (float4*)(xr2 + (size_t)n*HO);
#pragma unroll
    for (int q = 0; q < 4; q++) {
        xl4[q] = make_float4(ol[4*q], ol[4*q+1], ol[4*q+2], ol[4*q+3]);
        xr4[q] = make_float4(orr[4*q], orr[4*q+1], orr[4*q+2], orr[4*q+3]);
    }
}

// layer 2: aggregate (+bias, no act) then sum-pool into pool[16]
__global__ void __launch_bounds__(256) node_agg_l2(
    const int* __restrict__ row, const int* __restrict__ eperm,
    const float2* __restrict__ logits, const int* __restrict__ src,
    const float* __restrict__ xl, const float* __restrict__ bias,
    float* __restrict__ pool, int N)
{
    int n = blockIdx.x * 256 + threadIdx.x;
    float h[HO];
    if (n < N) {
        agg_node(n, row, eperm, logits, src, xl, bias, h);
    } else {
#pragma unroll
        for (int k = 0; k < HO; k++) h[k] = 0.f;
    }
#pragma unroll
    for (int off = 32; off > 0; off >>= 1) {
#pragma unroll
        for (int k = 0; k < HO; k++) h[k] += __shfl_down(h[k], off, 64);
    }
    if ((threadIdx.x & 63) == 0) {
#pragma unroll
        for (int k = 0; k < HO; k++) atomicAdd(&pool[k], h[k]);
    }
}

// ---------------- final tail ----------------
__global__ void __launch_bounds__(64) final_mlp(
    const float* __restrict__ pool, const float* __restrict__ meta,
    const float* __restrict__ sp1_w, const float* __restrict__ sp1_b,
    const float* __restrict__ sp2_w, const float* __restrict__ sp2_b,
    const float* __restrict__ me_w, const float* __restrict__ me_b,
    const float* __restrict__ fc1_w, const float* __restrict__ fc1_b,
    const float* __restrict__ fc2_w, const float* __restrict__ fc2_b,
    const float* __restrict__ fc3_w, const float* __restrict__ fc3_b,
    float* __restrict__ out)
{
    __shared__ float s1[64], zb[24], z1[24], z2[8];
    int t = threadIdx.x;
    {
        float acc = sp1_b[t];
        for (int k = 0; k < 16; k++) acc += pool[k]*sp1_w[t*16+k];
        s1[t] = lrelu(acc, 0.1f);
    }
    __syncthreads();
    if (t < 16) {
        float acc = sp2_b[t];
        for (int k = 0; k < 64; k++) acc += s1[k]*sp2_w[t*64+k];
        zb[t] = acc;
    } else if (t < 24) {
        int j = t - 16;
        float acc = me_b[j];
        for (int k = 0; k < 6; k++) acc += meta[k]*me_w[j*6+k];
        zb[t] = lrelu(acc, 0.1f);
    }
    __syncthreads();
    if (t < 24) {
        float acc = fc1_b[t];
        for (int k = 0; k < 24; k++) acc += zb[k]*fc1_w[t*24+k];
        z1[t] = lrelu(acc, 0.1f);
    }
    __syncthreads();
    if (t < 8) {
        float acc = fc2_b[t];
        for (int k = 0; k < 24; k++) acc += z1[k]*fc2_w[t*24+k];
        z2[t] = lrelu(acc, 0.1f);
    }
    __syncthreads();
    if (t == 0) {
        float z3[3]; float mxv = -1e30f;
        for (int j = 0; j < 3; j++) {
            float acc = fc3_b[j];
            for (int k = 0; k < 8; k++) acc += z2[k]*fc3_w[j*8+k];
            z3[j] = acc; mxv = fmaxf(mxv, acc);
        }
        float s = 0.f;
        for (int j = 0; j < 3; j++) { z3[j] = __expf(z3[j]-mxv); s += z3[j]; }
        for (int j = 0; j < 3; j++) out[j] = z3[j]/s;
    }
}

extern "C" void kernel_launch(void* const* d_in, const int* in_sizes, int n_in,
                              void* d_out, int out_size, void* d_ws, size_t ws_size,
                              hipStream_t stream)
{
    const float* x      = (const float*)d_in[0];
    const int*   eidx   = (const int*)  d_in[1];
    const float* eattr  = (const float*)d_in[2];
    const float* meta   = (const float*)d_in[3];
    const float* ft1_w  = (const float*)d_in[4];
    const float* ft1_b  = (const float*)d_in[5];
    const float* ft2_w  = (const float*)d_in[6];
    const float* ft2_b  = (const float*)d_in[7];
    const float* g1_wl  = (const float*)d_in[8];
    const float* g1_bl  = (const float*)d_in[9];
    const float* g1_wr  = (const float*)d_in[10];
    const float* g1_br  = (const float*)d_in[11];
    const float* g1_we  = (const float*)d_in[12];
    const float* g1_att = (const float*)d_in[13];
    const float* g1_bias= (const float*)d_in[14];
    const float* g2_wl  = (const float*)d_in[15];
    const float* g2_bl  = (const float*)d_in[16];
    const float* g2_wr  = (const float*)d_in[17];
    const float* g2_br  = (const float*)d_in[18];
    const float* g2_we  = (const float*)d_in[19];
    const float* g2_att = (const float*)d_in[20];
    const float* g2_bias= (const float*)d_in[21];
    const float* sp1_w  = (const float*)d_in[22];
    const float* sp1_b  = (const float*)d_in[23];
    const float* sp2_w  = (const float*)d_in[24];
    const float* sp2_b  = (const float*)d_in[25];
    const float* me_w   = (const float*)d_in[26];
    const float* me_b   = (const float*)d_in[27];
    const float* fc1_w  = (const float*)d_in[28];
    const float* fc1_b  = (const float*)d_in[29];
    const float* fc2_w  = (const float*)d_in[30];
    const float* fc2_b  = (const float*)d_in[31];
    const float* fc3_w  = (const float*)d_in[32];
    const float* fc3_b  = (const float*)d_in[33];
    float* out = (float*)d_out;

    const int N = in_sizes[0] / 3;
    const int E = in_sizes[2] / 2;
    const int* src = eidx;
    const int* dst = eidx + E;

    // workspace layout (256B-aligned chunks):
    //   row    : (N+1) int
    //   cursor : N int        (deg during build, then scatter cursors)
    //   bsum   : 1024 int
    //   pool   : 16 f32
    //   xl     : 16N f32
    //   xr     : 16N f32      (reused as h buffer between layers)
    //   eperm  : E int
    //   logits : E float2
    char* w = (char*)d_ws;
    size_t off = 0;
    auto take = [&](size_t bytes) { size_t o = off; off += (bytes + 255) & ~(size_t)255; return o; };
    int*    row    = (int*)   (w + take((size_t)4*(N+1)));
    int*    cursor = (int*)   (w + take((size_t)4*N));
    int*    bsum   = (int*)   (w + take(4096));
    float*  pool   = (float*) (w + take(64));
    float*  xl     = (float*) (w + take((size_t)64*N));
    float*  xr     = (float*) (w + take((size_t)64*N));   // also h buffer
    int*    eperm  = (int*)   (w + take((size_t)4*E));
    float2* logits = (float2*)(w + take((size_t)8*E));

    const int BN = (N + 255) / 256;
    const int BE = (E + 255) / 256;
    const int nb = BN;   // blocks of 256 over nodes; must be <= 1024 (N <= 262144)

    hipMemsetAsync(cursor, 0, (size_t)4*N, stream);
    hipMemsetAsync(pool, 0, 64, stream);

    // node features + layer-1 transforms (overlaps CSR build logically; same stream)
    node_l1<<<BN, 256, 0, stream>>>(x, ft1_w, ft1_b, ft2_w, ft2_b,
                                    g1_wl, g1_bl, g1_wr, g1_br, xl, xr, N);
    // CSR build (graph-only; shared by both layers)
    k_hist<<<BE, 256, 0, stream>>>(dst, cursor, E);
    k_scanA<<<nb, 256, 0, stream>>>(cursor, bsum, N);
    k_scanB<<<1, 1024, 0, stream>>>(bsum, nb);
    k_scanC<<<nb, 256, 0, stream>>>(cursor, bsum, row, N, E);
    k_scatter<<<BE, 256, 0, stream>>>(dst, cursor, eperm, E);

    // ---- layer 1 ----
    edge_logits<<<BE, 256, 0, stream>>>(src, dst, eattr, xl, xr, g1_we, g1_att, logits, E);
    node_agg_l1<<<BN, 256, 0, stream>>>(row, eperm, logits, src, xl, g1_bias, xr, N); // h -> xr buf
    node_transform<<<BN, 256, 0, stream>>>(xr, g2_wl, g2_bl, g2_wr, g2_br, xl, xr, N);
    // ---- layer 2 ----
    edge_logits<<<BE, 256, 0, stream>>>(src, dst, eattr, xl, xr, g2_we, g2_att, logits, E);
    node_agg_l2<<<BN, 256, 0, stream>>>(row, eperm, logits, src, xl, g2_bias, pool, N);
    // ---- tail ----
    final_mlp<<<1, 64, 0, stream>>>(pool, meta, sp1_w, sp1_b, sp2_w, sp2_b,
                                    me_w, me_b, fc1_w, fc1_b, fc2_w, fc2_b,
                                    fc3_w, fc3_b, out);
}

// Round 3
// 1055.405 us; speedup vs baseline: 10.3999x; 2.3594x over previous
//
#include <hip/hip_runtime.h>
#include <hip/hip_bf16.h>
#include <hip/hip_fp16.h>
#include <math.h>

// SportsGNN: ftMLP -> GATv2 x2 -> sumpool -> MLP -> softmax
// N=250000, E=5000000, H=2, O=8 (HO=16)
// Strategy: CSR-by-dst with fully permuted edge streams (src_perm, eattr_perm);
// per-(node,head) single-pass online-softmax aggregation with inline logits.
// No float atomics anywhere; pool via block partials.

#define HO 16

__device__ __forceinline__ float lrelu(float x, float s) { return x > 0.f ? x : s * x; }

// ---------------- node kernel, layer 1: x[N,3] -> ftMLP -> xl1,xr1 [N,16] ----------------
__global__ void __launch_bounds__(256) node_l1(
    const float* __restrict__ x,
    const float* __restrict__ ft1_w, const float* __restrict__ ft1_b,
    const float* __restrict__ ft2_w, const float* __restrict__ ft2_b,
    const float* __restrict__ wl, const float* __restrict__ bl,
    const float* __restrict__ wr, const float* __restrict__ br,
    float* __restrict__ xl, float* __restrict__ xr, int N)
{
    int n = blockIdx.x * 256 + threadIdx.x;
    if (n >= N) return;
    float x0 = x[3*n], x1 = x[3*n+1], x2 = x[3*n+2];
    float h1[8];
#pragma unroll
    for (int j = 0; j < 8; j++) {
        float a = ft1_w[3*j]*x0 + ft1_w[3*j+1]*x1 + ft1_w[3*j+2]*x2 + ft1_b[j];
        h1[j] = lrelu(a, 0.1f);
    }
    float h2[8];
#pragma unroll
    for (int j = 0; j < 8; j++) {
        float a = ft2_b[j];
#pragma unroll
        for (int k = 0; k < 8; k++) a += ft2_w[8*j+k]*h1[k];
        h2[j] = lrelu(a, 0.1f);
    }
    float ol[HO], orr[HO];
#pragma unroll
    for (int j = 0; j < HO; j++) {
        float a = bl[j], b = br[j];
#pragma unroll
        for (int k = 0; k < 8; k++) { a += wl[8*j+k]*h2[k]; b += wr[8*j+k]*h2[k]; }
        ol[j] = a; orr[j] = b;
    }
    float4* xl4 = (float4*)(xl + (size_t)n*HO);
    float4* xr4 = (float4*)(xr + (size_t)n*HO);
#pragma unroll
    for (int q = 0; q < 4; q++) {
        xl4[q] = make_float4(ol[4*q], ol[4*q+1], ol[4*q+2], ol[4*q+3]);
        xr4[q] = make_float4(orr[4*q], orr[4*q+1], orr[4*q+2], orr[4*q+3]);
    }
}

// ---------------- CSR build ----------------
__global__ void __launch_bounds__(256) k_hist(
    const int* __restrict__ dst, int* __restrict__ deg, int E)
{
    int e = blockIdx.x * 256 + threadIdx.x;
    if (e < E) atomicAdd(&deg[dst[e]], 1);
}

__global__ void __launch_bounds__(256) k_scanA(
    const int* __restrict__ deg, int* __restrict__ bsum, int N)
{
    __shared__ int r[256];
    int t = threadIdx.x;
    int n = blockIdx.x * 256 + t;
    r[t] = (n < N) ? deg[n] : 0;
    __syncthreads();
#pragma unroll
    for (int off = 128; off > 0; off >>= 1) {
        if (t < off) r[t] += r[t + off];
        __syncthreads();
    }
    if (t == 0) bsum[blockIdx.x] = r[0];
}

__global__ void __launch_bounds__(1024) k_scanB(int* __restrict__ bsum, int nb)
{
    __shared__ int s[1024];
    int t = threadIdx.x;
    int v = (t < nb) ? bsum[t] : 0;
    s[t] = v;
    __syncthreads();
    for (int off = 1; off < 1024; off <<= 1) {
        int add = (t >= off) ? s[t - off] : 0;
        __syncthreads();
        s[t] += add;
        __syncthreads();
    }
    if (t < nb) bsum[t] = s[t] - v;   // exclusive
}

__global__ void __launch_bounds__(256) k_scanC(
    int* deg_cursor, const int* __restrict__ bsum,
    int* __restrict__ row, int N, int E)
{
    __shared__ int s[256];
    int t = threadIdx.x;
    int n = blockIdx.x * 256 + t;
    int d = (n < N) ? deg_cursor[n] : 0;
    s[t] = d;
    __syncthreads();
    for (int off = 1; off < 256; off <<= 1) {
        int add = (t >= off) ? s[t - off] : 0;
        __syncthreads();
        s[t] += add;
        __syncthreads();
    }
    int val = bsum[blockIdx.x] + s[t] - d;   // exclusive prefix
    if (n < N) { row[n] = val; deg_cursor[n] = val; }
    if (n == 0) row[N] = E;
}

// scatter: build permuted edge streams (src, eattr as half2) in dst-sorted order
__global__ void __launch_bounds__(256) k_scatter(
    const int* __restrict__ src, const int* __restrict__ dst,
    const float* __restrict__ eattr, int* __restrict__ cursor,
    int* __restrict__ src_perm, __half2* __restrict__ eattr_perm, int E)
{
    int e = blockIdx.x * 256 + threadIdx.x;
    if (e >= E) return;
    int pos = atomicAdd(&cursor[dst[e]], 1);
    src_perm[pos] = src[e];
    float2 ea = ((const float2*)eattr)[e];
    eattr_perm[pos] = __floats2half2_rn(ea.x, ea.y);
}

// ---------------- per-(node,head) online-softmax aggregation ----------------
// Per edge: logit = sum_o att[k] * lrelu0.2( xl[s][k] + xr[n][k] + we[k]·ea ), k=h*8+o
// out[o] = (sum_e exp(lg-m)*xl[s][k]) / (sum_e exp(lg-m)) + bias[k]
struct AggState {
    float m, s;
    float acc[8];
};

__device__ __forceinline__ void agg_edge(
    AggState& st, const float* va, const float* xd,
    const float* w0, const float* w1, const float* at,
    float ea0, float ea1)
{
    float lg = 0.f;
#pragma unroll
    for (int o = 0; o < 8; o++) {
        float mv = va[o] + xd[o] + (w0[o]*ea0 + w1[o]*ea1);
        mv = mv > 0.f ? mv : 0.2f*mv;
        lg += mv * at[o];
    }
    float nm = fmaxf(st.m, lg);
    float sc = __expf(st.m - nm);
    float wv = __expf(lg - nm);
    st.s = st.s*sc + wv;
#pragma unroll
    for (int o = 0; o < 8; o++) st.acc[o] = st.acc[o]*sc + wv*va[o];
    st.m = nm;
}

// shared body: computes out[0..7] = agg + bias for (n, h)
__device__ __forceinline__ void agg_node_head(
    int n, int h,
    const int* __restrict__ row, const int* __restrict__ src_perm,
    const __half2* __restrict__ eattr_perm,
    const float* __restrict__ xl, const float* __restrict__ xr,
    const float* __restrict__ we, const float* __restrict__ att,
    const float* __restrict__ bias, float* out)
{
    int kb = h*8;
    float xd[8], w0[8], w1[8], at[8];
    {
        const float4* xrp = (const float4*)(xr + (size_t)n*HO + kb);
        float4 d0 = xrp[0], d1 = xrp[1];
        xd[0]=d0.x; xd[1]=d0.y; xd[2]=d0.z; xd[3]=d0.w;
        xd[4]=d1.x; xd[5]=d1.y; xd[6]=d1.z; xd[7]=d1.w;
    }
#pragma unroll
    for (int o = 0; o < 8; o++) {
        w0[o] = we[2*(kb+o)];
        w1[o] = we[2*(kb+o)+1];
        at[o] = att[kb+o];
    }
    AggState st;
    st.m = -INFINITY; st.s = 0.f;
#pragma unroll
    for (int o = 0; o < 8; o++) st.acc[o] = 0.f;

    int i = row[n], end = row[n+1];
    // 2-wide software pipeline: issue both gathers before the serial update
    for (; i + 2 <= end; i += 2) {
        int   sA = src_perm[i],  sB = src_perm[i+1];
        __half2 eA = eattr_perm[i], eB = eattr_perm[i+1];
        const float4* pA = (const float4*)(xl + (size_t)sA*HO + kb);
        const float4* pB = (const float4*)(xl + (size_t)sB*HO + kb);
        float4 a0 = pA[0], a1 = pA[1];
        float4 b0 = pB[0], b1 = pB[1];
        float vA[8] = {a0.x,a0.y,a0.z,a0.w,a1.x,a1.y,a1.z,a1.w};
        float vB[8] = {b0.x,b0.y,b0.z,b0.w,b1.x,b1.y,b1.z,b1.w};
        agg_edge(st, vA, xd, w0, w1, at, __low2float(eA), __high2float(eA));
        agg_edge(st, vB, xd, w0, w1, at, __low2float(eB), __high2float(eB));
    }
    if (i < end) {
        int sA = src_perm[i];
        __half2 eA = eattr_perm[i];
        const float4* pA = (const float4*)(xl + (size_t)sA*HO + kb);
        float4 a0 = pA[0], a1 = pA[1];
        float vA[8] = {a0.x,a0.y,a0.z,a0.w,a1.x,a1.y,a1.z,a1.w};
        agg_edge(st, vA, xd, w0, w1, at, __low2float(eA), __high2float(eA));
    }
    float inv = 1.f/(st.s + 1e-16f);
#pragma unroll
    for (int o = 0; o < 8; o++) out[o] = st.acc[o]*inv + bias[kb+o];
}

// layer 1: + lrelu(0.1), write h buffer
__global__ void __launch_bounds__(256) node_agg_l1(
    const int* __restrict__ row, const int* __restrict__ src_perm,
    const __half2* __restrict__ eattr_perm,
    const float* __restrict__ xl, const float* __restrict__ xr,
    const float* __restrict__ we, const float* __restrict__ att,
    const float* __restrict__ bias, float* __restrict__ hout, int N)
{
    int tid = blockIdx.x * 256 + threadIdx.x;
    int n = tid >> 1, h = tid & 1;
    if (n >= N) return;
    float out[8];
    agg_node_head(n, h, row, src_perm, eattr_perm, xl, xr, we, att, bias, out);
    float4* hp = (float4*)(hout + (size_t)n*HO + h*8);
    hp[0] = make_float4(lrelu(out[0],0.1f), lrelu(out[1],0.1f), lrelu(out[2],0.1f), lrelu(out[3],0.1f));
    hp[1] = make_float4(lrelu(out[4],0.1f), lrelu(out[5],0.1f), lrelu(out[6],0.1f), lrelu(out[7],0.1f));
}

// transform h by layer-2 weights -> xl2, xr2
__global__ void __launch_bounds__(256) node_transform(
    const float* __restrict__ hin,
    const float* __restrict__ wl2, const float* __restrict__ bl2,
    const float* __restrict__ wr2, const float* __restrict__ br2,
    float* __restrict__ xl2, float* __restrict__ xr2, int N)
{
    int n = blockIdx.x * 256 + threadIdx.x;
    if (n >= N) return;
    float h[HO];
    const float4* hp = (const float4*)(hin + (size_t)n*HO);
#pragma unroll
    for (int q = 0; q < 4; q++) {
        float4 v = hp[q];
        h[4*q]=v.x; h[4*q+1]=v.y; h[4*q+2]=v.z; h[4*q+3]=v.w;
    }
    float ol[HO], orr[HO];
#pragma unroll
    for (int j = 0; j < HO; j++) {
        float a = bl2[j], b = br2[j];
#pragma unroll
        for (int k = 0; k < HO; k++) { a += wl2[HO*j+k]*h[k]; b += wr2[HO*j+k]*h[k]; }
        ol[j] = a; orr[j] = b;
    }
    float4* xl4 = (float4*)(xl2 + (size_t)n*HO);
    float4* xr4 = (float4*)(xr2 + (size_t)n*HO);
#pragma unroll
    for (int q = 0; q < 4; q++) {
        xl4[q] = make_float4(ol[4*q], ol[4*q+1], ol[4*q+2], ol[4*q+3]);
        xr4[q] = make_float4(orr[4*q], orr[4*q+1], orr[4*q+2], orr[4*q+3]);
    }
}

// layer 2: aggregate (+bias, no act), block-reduce, write per-block partials[16]
__global__ void __launch_bounds__(256) node_agg_l2(
    const int* __restrict__ row, const int* __restrict__ src_perm,
    const __half2* __restrict__ eattr_perm,
    const float* __restrict__ xl, const float* __restrict__ xr,
    const float* __restrict__ we, const float* __restrict__ att,
    const float* __restrict__ bias, float* __restrict__ partials, int N)
{
    int tid = blockIdx.x * 256 + threadIdx.x;
    int n = tid >> 1, h = tid & 1;
    float out[8];
    if (n < N) {
        agg_node_head(n, h, row, src_perm, eattr_perm, xl, xr, we, att, bias, out);
    } else {
#pragma unroll
        for (int o = 0; o < 8; o++) out[o] = 0.f;
    }
    // wave reduce over same-parity lanes (heads interleave even/odd)
#pragma unroll
    for (int off = 32; off >= 2; off >>= 1) {
#pragma unroll
        for (int o = 0; o < 8; o++) out[o] += __shfl_down(out[o], off, 64);
    }
    __shared__ float sm[4][2][8];
    int wave = threadIdx.x >> 6, lane = threadIdx.x & 63;
    if (lane < 2) {
#pragma unroll
        for (int o = 0; o < 8; o++) sm[wave][lane][o] = out[o];
    }
    __syncthreads();
    if (threadIdx.x < 16) {
        int hh = threadIdx.x >> 3, oo = threadIdx.x & 7;
        float t = sm[0][hh][oo] + sm[1][hh][oo] + sm[2][hh][oo] + sm[3][hh][oo];
        partials[(size_t)blockIdx.x*16 + hh*8 + oo] = t;
    }
}

// ---------------- final tail: sum partials -> pool, then MLP chain + softmax ----------------
__global__ void __launch_bounds__(64) final_mlp(
    const float* __restrict__ partials, int nparts,
    const float* __restrict__ meta,
    const float* __restrict__ sp1_w, const float* __restrict__ sp1_b,
    const float* __restrict__ sp2_w, const float* __restrict__ sp2_b,
    const float* __restrict__ me_w, const float* __restrict__ me_b,
    const float* __restrict__ fc1_w, const float* __restrict__ fc1_b,
    const float* __restrict__ fc2_w, const float* __restrict__ fc2_b,
    const float* __restrict__ fc3_w, const float* __restrict__ fc3_b,
    float* __restrict__ out)
{
    __shared__ float red[4][16];
    __shared__ float pool[16];
    __shared__ float s1[64], zb[24], z1[24], z2[8];
    int t = threadIdx.x;
    {   // sum partials: thread t handles column t&15, rows (t>>4)::4
        int col = t & 15, r0 = t >> 4;
        float acc = 0.f;
        for (int r = r0; r < nparts; r += 4) acc += partials[(size_t)r*16 + col];
        red[r0][col] = acc;
    }
    __syncthreads();
    if (t < 16) pool[t] = red[0][t] + red[1][t] + red[2][t] + red[3][t];
    __syncthreads();
    {
        float acc = sp1_b[t];
        for (int k = 0; k < 16; k++) acc += pool[k]*sp1_w[t*16+k];
        s1[t] = lrelu(acc, 0.1f);
    }
    __syncthreads();
    if (t < 16) {
        float acc = sp2_b[t];
        for (int k = 0; k < 64; k++) acc += s1[k]*sp2_w[t*64+k];
        zb[t] = acc;
    } else if (t < 24) {
        int j = t - 16;
        float acc = me_b[j];
        for (int k = 0; k < 6; k++) acc += meta[k]*me_w[j*6+k];
        zb[t] = lrelu(acc, 0.1f);
    }
    __syncthreads();
    if (t < 24) {
        float acc = fc1_b[t];
        for (int k = 0; k < 24; k++) acc += zb[k]*fc1_w[t*24+k];
        z1[t] = lrelu(acc, 0.1f);
    }
    __syncthreads();
    if (t < 8) {
        float acc = fc2_b[t];
        for (int k = 0; k < 24; k++) acc += z1[k]*fc2_w[t*24+k];
        z2[t] = lrelu(acc, 0.1f);
    }
    __syncthreads();
    if (t == 0) {
        float z3[3]; float mxv = -1e30f;
        for (int j = 0; j < 3; j++) {
            float acc = fc3_b[j];
            for (int k = 0; k < 8; k++) acc += z2[k]*fc3_w[j*8+k];
            z3[j] = acc; mxv = fmaxf(mxv, acc);
        }
        float s = 0.f;
        for (int j = 0; j < 3; j++) { z3[j] = __expf(z3[j]-mxv); s += z3[j]; }
        for (int j = 0; j < 3; j++) out[j] = z3[j]/s;
    }
}

extern "C" void kernel_launch(void* const* d_in, const int* in_sizes, int n_in,
                              void* d_out, int out_size, void* d_ws, size_t ws_size,
                              hipStream_t stream)
{
    const float* x      = (const float*)d_in[0];
    const int*   eidx   = (const int*)  d_in[1];
    const float* eattr  = (const float*)d_in[2];
    const float* meta   = (const float*)d_in[3];
    const float* ft1_w  = (const float*)d_in[4];
    const float* ft1_b  = (const float*)d_in[5];
    const float* ft2_w  = (const float*)d_in[6];
    const float* ft2_b  = (const float*)d_in[7];
    const float* g1_wl  = (const float*)d_in[8];
    const float* g1_bl  = (const float*)d_in[9];
    const float* g1_wr  = (const float*)d_in[10];
    const float* g1_br  = (const float*)d_in[11];
    const float* g1_we  = (const float*)d_in[12];
    const float* g1_att = (const float*)d_in[13];
    const float* g1_bias= (const float*)d_in[14];
    const float* g2_wl  = (const float*)d_in[15];
    const float* g2_bl  = (const float*)d_in[16];
    const float* g2_wr  = (const float*)d_in[17];
    const float* g2_br  = (const float*)d_in[18];
    const float* g2_we  = (const float*)d_in[19];
    const float* g2_att = (const float*)d_in[20];
    const float* g2_bias= (const float*)d_in[21];
    const float* sp1_w  = (const float*)d_in[22];
    const float* sp1_b  = (const float*)d_in[23];
    const float* sp2_w  = (const float*)d_in[24];
    const float* sp2_b  = (const float*)d_in[25];
    const float* me_w   = (const float*)d_in[26];
    const float* me_b   = (const float*)d_in[27];
    const float* fc1_w  = (const float*)d_in[28];
    const float* fc1_b  = (const float*)d_in[29];
    const float* fc2_w  = (const float*)d_in[30];
    const float* fc2_b  = (const float*)d_in[31];
    const float* fc3_w  = (const float*)d_in[32];
    const float* fc3_b  = (const float*)d_in[33];
    float* out = (float*)d_out;

    const int N = in_sizes[0] / 3;
    const int E = in_sizes[2] / 2;
    const int* src = eidx;
    const int* dst = eidx + E;

    const int BN  = (N + 255) / 256;
    const int BE  = (E + 255) / 256;
    const int BN2 = (2*N + 255) / 256;   // agg kernels: 2 threads/node
    const int nb  = BN;                  // must be <= 1024 (N <= 262144)

    // workspace layout (256B-aligned):
    char* w = (char*)d_ws;
    size_t off = 0;
    auto take = [&](size_t bytes) { size_t o = off; off += (bytes + 255) & ~(size_t)255; return o; };
    int*     row        = (int*)    (w + take((size_t)4*(N+1)));
    int*     cursor     = (int*)    (w + take((size_t)4*N));
    int*     bsum       = (int*)    (w + take(4096));
    float*   partials   = (float*)  (w + take((size_t)4*16*BN2));
    int*     src_perm   = (int*)    (w + take((size_t)4*E));
    __half2* eattr_perm = (__half2*)(w + take((size_t)4*E));
    float*   xl         = (float*)  (w + take((size_t)64*N));
    float*   xr         = (float*)  (w + take((size_t)64*N));
    float*   hbuf       = (float*)  (w + take((size_t)64*N));
    // total ~= 2MB + 125KB + 20MB + 20MB + 48MB ~= 90MB

    hipMemsetAsync(cursor, 0, (size_t)4*N, stream);

    // node features + layer-1 transforms
    node_l1<<<BN, 256, 0, stream>>>(x, ft1_w, ft1_b, ft2_w, ft2_b,
                                    g1_wl, g1_bl, g1_wr, g1_br, xl, xr, N);
    // CSR build + permuted edge streams (graph-only; shared by both layers)
    k_hist<<<BE, 256, 0, stream>>>(dst, cursor, E);
    k_scanA<<<nb, 256, 0, stream>>>(cursor, bsum, N);
    k_scanB<<<1, 1024, 0, stream>>>(bsum, nb);
    k_scanC<<<nb, 256, 0, stream>>>(cursor, bsum, row, N, E);
    k_scatter<<<BE, 256, 0, stream>>>(src, dst, eattr, cursor, src_perm, eattr_perm, E);

    // ---- layer 1 ----
    node_agg_l1<<<BN2, 256, 0, stream>>>(row, src_perm, eattr_perm, xl, xr,
                                         g1_we, g1_att, g1_bias, hbuf, N);
    node_transform<<<BN, 256, 0, stream>>>(hbuf, g2_wl, g2_bl, g2_wr, g2_br, xl, xr, N);
    // ---- layer 2 ----
    node_agg_l2<<<BN2, 256, 0, stream>>>(row, src_perm, eattr_perm, xl, xr,
                                         g2_we, g2_att, g2_bias, partials, N);
    // ---- tail ----
    final_mlp<<<1, 64, 0, stream>>>(partials, BN2, meta, sp1_w, sp1_b, sp2_w, sp2_b,
                                    me_w, me_b, fc1_w, fc1_b, fc2_w, fc2_b,
                                    fc3_w, fc3_b, out);
}